// Round 3
// baseline (732.780 us; speedup 1.0000x reference)
//
#include <hip/hip_runtime.h>

#define TPB 512

typedef __attribute__((ext_vector_type(16))) float    fv16;
typedef __attribute__((ext_vector_type(16))) unsigned uv16;

__device__ __forceinline__ unsigned bf16_rne(float f) {
    unsigned u = __float_as_uint(f);
    return (u + 0x7fffu + ((u >> 16) & 1u)) >> 16;
}

// One block per sample (128 blocks, each alone on a CU). 512 threads:
//   thread t owns h_t: W1 column t in fp32 held in 8 NAMED float16 vectors (128 VGPR)
//   thread t owns W2[kb..kb+127][j] (j=t&127, kb=128*(t>>7)) as 4 NAMED uint16 vectors
//   of packed bf16 pairs (64 VGPR).
// Named ext_vectors + compile-time-constant subscripts only => pure SSA values,
// no alloca => cannot be demoted to scratch (plain arrays were: VGPR=128 +
// 22.8 MB spill WRITE_SIZE + L2 reload every eval = 211 us).
__global__ __launch_bounds__(TPB, 1) void vi_node_kernel(
    const float* __restrict__ x0, const float* __restrict__ W1,
    const float* __restrict__ b1, const float* __restrict__ u1,
    const float* __restrict__ W2, const float* __restrict__ b2,
    const int* __restrict__ nsp, float* __restrict__ out, int nB)
{
    const int s    = blockIdx.x;
    const int t    = threadIdx.x;
    const int j    = t & 127;
    const int kb   = (t >> 7) << 7;
    const int q    = t >> 7;
    const int lane = t & 63;
    const int wid  = t >> 6;

    __shared__ __align__(16) float xs[128];      // stage input
    __shared__ __align__(16) float ys[128];      // base state y_n
    __shared__ __align__(16) float aL[512];      // tanh activations
    __shared__ __align__(16) float part[4][128]; // dxdt partials
    __shared__ __align__(16) float kx[6][128];   // RK stage slopes
    __shared__ float wred[16];                   // wave partial sums
    __shared__ float klpS[6], kklS[6];           // scalar stage slopes

    fv16 A0, A1, A2, A3, A4, A5, A6, A7;   // W1 column t, fp32
    uv16 Z0, Z1, Z2, Z3;                   // W2 rows kb..kb+127 col j, packed bf16

    // ---- W1 column load (coalesced across t for each row) ----
#define LW1E(V,K,B) V[K] = W1[((B)+(K))*512 + t];
#define LW1G(V,B) LW1E(V,0,B) LW1E(V,1,B) LW1E(V,2,B) LW1E(V,3,B) LW1E(V,4,B) \
    LW1E(V,5,B) LW1E(V,6,B) LW1E(V,7,B) LW1E(V,8,B) LW1E(V,9,B) LW1E(V,10,B) \
    LW1E(V,11,B) LW1E(V,12,B) LW1E(V,13,B) LW1E(V,14,B) LW1E(V,15,B)
    LW1G(A0,0) LW1G(A1,16) LW1G(A2,32) LW1G(A3,48)
    LW1G(A4,64) LW1G(A5,80) LW1G(A6,96) LW1G(A7,112)

    // ---- W2 pack load: Z_B[K] packs rows kb+32B+2K (lo) and +1 (hi), col j ----
#define LW2E(V,K,B) { float lo_ = W2[((kb)+(B)+2*(K))*128 + j]; \
                      float hi_ = W2[((kb)+(B)+2*(K)+1)*128 + j]; \
                      V[K] = bf16_rne(lo_) | (bf16_rne(hi_) << 16); }
#define LW2G(V,B) LW2E(V,0,B) LW2E(V,1,B) LW2E(V,2,B) LW2E(V,3,B) LW2E(V,4,B) \
    LW2E(V,5,B) LW2E(V,6,B) LW2E(V,7,B) LW2E(V,8,B) LW2E(V,9,B) LW2E(V,10,B) \
    LW2E(V,11,B) LW2E(V,12,B) LW2E(V,13,B) LW2E(V,14,B) LW2E(V,15,B)
    LW2G(Z0,0) LW2G(Z1,32) LW2G(Z2,64) LW2G(Z3,96)

    // ---- wdiag_t = sum_i W1[i,t] * W2[t,i]  (exact fp32, one-time) ----
    float wd = 0.f;
    {
        const float* w2row = W2 + t * 128;
#define WDE(V,K,B) wd = fmaf(V[K], w2row[(B)+(K)], wd);
#define WDG(V,B) WDE(V,0,B) WDE(V,1,B) WDE(V,2,B) WDE(V,3,B) WDE(V,4,B) \
    WDE(V,5,B) WDE(V,6,B) WDE(V,7,B) WDE(V,8,B) WDE(V,9,B) WDE(V,10,B) \
    WDE(V,11,B) WDE(V,12,B) WDE(V,13,B) WDE(V,14,B) WDE(V,15,B)
        WDG(A0,0) WDG(A1,16) WDG(A2,32) WDG(A3,48)
        WDG(A4,64) WDG(A5,80) WDG(A6,96) WDG(A7,112)
    }

    const float b1k = b1[t];
    const float u1k = u1[t];
    const float b2j = b2[j];

    const int ns = nsp[0];
    const float dt = 1.f / (float)ns;

    // ---- init state + log_px0 sum of squares ----
    if (t < 128) {
        float xv = x0[s * 128 + t];
        ys[t] = xv;
        xs[t] = xv;
        float sq = xv * xv;
#pragma unroll
        for (int off = 32; off; off >>= 1) sq += __shfl_xor(sq, off, 64);
        if (lane == 0) wred[8 + wid] = sq;
    }
    __syncthreads();
    const float sumsq = wred[8] + wred[9];
    float ld_acc = 0.f, kl_acc = 0.f;

    // ---- per-eval compute blocks (all subscripts compile-time constant) ----
#define HB(V,K,O) { float4 xv_ = *(const float4*)&xs[(O)]; \
    h0 = fmaf(xv_.x, V[K],     h0); h1 = fmaf(xv_.y, V[(K)+1], h1); \
    h2 = fmaf(xv_.z, V[(K)+2], h2); h3 = fmaf(xv_.w, V[(K)+3], h3); }
#define HG(V,B) HB(V,0,(B)) HB(V,4,(B)+4) HB(V,8,(B)+8) HB(V,12,(B)+12)

#define PB(V,K,O) { float4 av_ = *(const float4*)&aL[kb + (O)]; \
    unsigned wA_ = V[K], wB_ = V[(K)+1]; \
    p0 = fmaf(av_.x, __uint_as_float(wA_ << 16),         p0); \
    p1 = fmaf(av_.y, __uint_as_float(wA_ & 0xffff0000u), p1); \
    p2 = fmaf(av_.z, __uint_as_float(wB_ << 16),         p2); \
    p3 = fmaf(av_.w, __uint_as_float(wB_ & 0xffff0000u), p3); }
#define PG(V,B) PB(V,0,(B)) PB(V,2,(B)+4) PB(V,4,(B)+8) PB(V,6,(B)+12) \
    PB(V,8,(B)+16) PB(V,10,(B)+20) PB(V,12,(B)+24) PB(V,14,(B)+28)

// One RHS eval: reads xs, writes kx[STAGE], klpS/kklS[STAGE]. 3 internal barriers.
#define EVAL(STAGE, TVAL)                                                      \
    {                                                                          \
        float h0 = 0.f, h1 = 0.f, h2 = 0.f, h3 = 0.f;                          \
        HG(A0,0) HG(A1,16) HG(A2,32) HG(A3,48)                                 \
        HG(A4,64) HG(A5,80) HG(A6,96) HG(A7,112)                               \
        float hh = fmaf((TVAL), u1k, b1k) + ((h0 + h1) + (h2 + h3));           \
        float ee = __expf(2.f * hh);                                           \
        float aa = 1.f - 2.f / (ee + 1.f);       /* tanh */                    \
        aL[t] = aa;                                                            \
        float trp = (1.f - aa * aa) * wd;                                      \
        _Pragma("unroll")                                                      \
        for (int off = 32; off; off >>= 1) trp += __shfl_xor(trp, off, 64);    \
        if (lane == 0) wred[wid] = trp;                                        \
        __syncthreads();                          /* B1: a + tr partials */    \
        float p0 = 0.f, p1 = 0.f, p2 = 0.f, p3 = 0.f;                          \
        PG(Z0,0) PG(Z1,32) PG(Z2,64) PG(Z3,96)                                 \
        part[q][j] = (p0 + p1) + (p2 + p3);                                    \
        __syncthreads();                          /* B2: partials ready */     \
        if (t < 128) {                                                         \
            float dx = ((part[0][t] + part[1][t]) + (part[2][t] + part[3][t])) \
                       + b2j;                                                  \
            kx[STAGE][t] = dx;                                                 \
            float xd = xs[t] * dx;                                             \
            _Pragma("unroll")                                                  \
            for (int off = 32; off; off >>= 1) xd += __shfl_xor(xd, off, 64);  \
            if (lane == 0) wred[8 + wid] = xd;                                 \
        }                                                                      \
        __syncthreads();                          /* B3: kx + dot partials */  \
        if (t == 0) {                                                          \
            float tr = ((wred[0] + wred[1]) + (wred[2] + wred[3]))             \
                     + ((wred[4] + wred[5]) + (wred[6] + wred[7]));            \
            float dotv = wred[8] + wred[9];                                    \
            klpS[STAGE] = -tr;                                                 \
            kklS[STAGE] = dotv - tr;                                           \
        }                                                                      \
    }

    for (int n = 0; n < ns; ++n) {
        const float tn = (float)n;

        EVAL(0, dt * tn);
        if (t < 128) xs[t] = fmaf(dt, 0.2f * kx[0][t], ys[t]);
        __syncthreads();

        EVAL(1, dt * (tn + 0.2f));
        if (t < 128) xs[t] = fmaf(dt, 0.075f * kx[0][t] + 0.225f * kx[1][t], ys[t]);
        __syncthreads();

        EVAL(2, dt * (tn + 0.3f));
        if (t < 128) xs[t] = fmaf(dt,
              (float)(44.0/45.0)  * kx[0][t] + (float)(-56.0/15.0) * kx[1][t]
            + (float)(32.0/9.0)   * kx[2][t], ys[t]);
        __syncthreads();

        EVAL(3, dt * (tn + 0.8f));
        if (t < 128) xs[t] = fmaf(dt,
              (float)(19372.0/6561.0)  * kx[0][t] + (float)(-25360.0/2187.0) * kx[1][t]
            + (float)(64448.0/6561.0)  * kx[2][t] + (float)(-212.0/729.0)    * kx[3][t], ys[t]);
        __syncthreads();

        EVAL(4, dt * (tn + (float)(8.0/9.0)));
        if (t < 128) xs[t] = fmaf(dt,
              (float)(9017.0/3168.0)   * kx[0][t] + (float)(-355.0/33.0)     * kx[1][t]
            + (float)(46732.0/5247.0)  * kx[2][t] + (float)(49.0/176.0)      * kx[3][t]
            + (float)(-5103.0/18656.0) * kx[4][t], ys[t]);
        __syncthreads();

        EVAL(5, dt * (tn + 1.0f));
        if (t < 128) {
            float sum = (float)(35.0/384.0)    * kx[0][t] + (float)(500.0/1113.0)   * kx[2][t]
                      + (float)(125.0/192.0)   * kx[3][t] + (float)(-2187.0/6784.0) * kx[4][t]
                      + (float)(11.0/84.0)     * kx[5][t];
            float yv = fmaf(dt, sum, ys[t]);
            ys[t] = yv;
            xs[t] = yv;
        }
        if (t == 0) {
            ld_acc += dt * ((float)(35.0/384.0)  * klpS[0] + (float)(500.0/1113.0)   * klpS[2]
                          + (float)(125.0/192.0) * klpS[3] + (float)(-2187.0/6784.0) * klpS[4]
                          + (float)(11.0/84.0)   * klpS[5]);
            kl_acc += dt * ((float)(35.0/384.0)  * kklS[0] + (float)(500.0/1113.0)   * kklS[2]
                          + (float)(125.0/192.0) * kklS[3] + (float)(-2187.0/6784.0) * kklS[4]
                          + (float)(11.0/84.0)   * kklS[5]);
        }
        __syncthreads();
    }

    // ---- outputs: z (B,D) | log_px (B) | kl (B) ----
    if (t < 128) out[s * 128 + t] = ys[t];
    if (t == 0) {
        const float LOG2PI = 1.8378770664093454f;
        float lpx0 = -0.5f * sumsq - 0.5f * 128.f * LOG2PI;
        out[nB * 128 + s]      = lpx0 + ld_acc;
        out[nB * 128 + nB + s] = kl_acc;
    }
}

extern "C" void kernel_launch(void* const* d_in, const int* in_sizes, int n_in,
                              void* d_out, int out_size, void* d_ws, size_t ws_size,
                              hipStream_t stream) {
    const float* x0 = (const float*)d_in[0];
    const float* W1 = (const float*)d_in[1];
    const float* b1 = (const float*)d_in[2];
    const float* u1 = (const float*)d_in[3];
    const float* W2 = (const float*)d_in[4];
    const float* b2 = (const float*)d_in[5];
    const int*  nsp = (const int*)d_in[6];
    float* out = (float*)d_out;
    const int nB = in_sizes[0] / 128;   // 128 samples

    hipLaunchKernelGGL(vi_node_kernel, dim3(nB), dim3(TPB), 0, stream,
                       x0, W1, b1, u1, W2, b2, nsp, out, nB);
}

// Round 4
// 716.796 us; speedup vs baseline: 1.0223x; 1.0223x over previous
//
#include <hip/hip_runtime.h>

#define TPB 512

__device__ __forceinline__ unsigned bf16_rne(float f) {
    unsigned u = __float_as_uint(f);
    return (u + 0x7fffu + ((u >> 16) & 1u)) >> 16;
}

// X-macro group expanders
#define G32(M) M(0) M(1) M(2) M(3) M(4) M(5) M(6) M(7) M(8) M(9) M(10) M(11) \
  M(12) M(13) M(14) M(15) M(16) M(17) M(18) M(19) M(20) M(21) M(22) M(23) \
  M(24) M(25) M(26) M(27) M(28) M(29) M(30) M(31)
#define G16(M) M(0) M(1) M(2) M(3) M(4) M(5) M(6) M(7) M(8) M(9) M(10) M(11) \
  M(12) M(13) M(14) M(15)

// One block per sample (128 blocks, each alone on a CU; grid < 256 CUs so
// >2 waves/SIMD buys nothing). Persistent per-thread state as NAMED SCALARS:
//   w1_g_k : W1 column t in fp32 (128 VGPR)  [thread t owns hidden unit t]
//   z_g_k  : W2 rows kb..kb+127, col j, packed bf16 pairs (64 VGPR)
// amdgpu_waves_per_eu(2,2): raises the VGPR cap to 512/2 = 256 (the backend's
// default 4 waves/EU capped us at 128 -> everything spilled: 40 MB scratch
// writes, 700 us). Scalars (not ext_vectors) avoid VReg_512 contiguity
// constraints that made round-3 regalloc shatter.
__global__ __attribute__((amdgpu_flat_work_group_size(TPB, TPB),
                          amdgpu_waves_per_eu(2, 2)))
void vi_node_kernel(
    const float* __restrict__ x0, const float* __restrict__ W1,
    const float* __restrict__ b1, const float* __restrict__ u1,
    const float* __restrict__ W2, const float* __restrict__ b2,
    const int* __restrict__ nsp, float* __restrict__ out, int nB)
{
    const int s    = blockIdx.x;
    const int t    = threadIdx.x;
    const int j    = t & 127;
    const int q    = t >> 7;
    const int kb   = q << 7;
    const int lane = t & 63;
    const int wid  = t >> 6;

    __shared__ __align__(16) float xs[128];      // stage input
    __shared__ __align__(16) float ys[128];      // base state y_n
    __shared__ __align__(16) float aL[512];      // tanh activations
    __shared__ __align__(16) float part[4][128]; // dxdt partials
    __shared__ __align__(16) float kx[6][128];   // RK stage slopes
    __shared__ float wred[16];                   // wave partial sums
    __shared__ float klpS[6], kklS[6];           // scalar stage slopes

    // ---- persistent register state (named scalars, SSA) ----
#define DECLW1(g) float w1_##g##_0, w1_##g##_1, w1_##g##_2, w1_##g##_3;
    G32(DECLW1)
#define DECLZ(g) unsigned z_##g##_0, z_##g##_1, z_##g##_2, z_##g##_3;
    G16(DECLZ)

    // ---- W1 column load (coalesced across t for each row) ----
#define LOADW1(g) { const float* p_ = W1 + (4*(g))*512 + t; \
    w1_##g##_0 = p_[0]; w1_##g##_1 = p_[512]; w1_##g##_2 = p_[1024]; w1_##g##_3 = p_[1536]; }
    G32(LOADW1)

    // ---- W2 pack load: column j, rows kb+8g .. kb+8g+7, bf16 pairs ----
#define PK2(r) (bf16_rne(W2[(r)*128 + j]) | (bf16_rne(W2[((r)+1)*128 + j]) << 16))
#define LOADZ(g) { const int r_ = kb + 8*(g); \
    z_##g##_0 = PK2(r_);     z_##g##_1 = PK2(r_ + 2); \
    z_##g##_2 = PK2(r_ + 4); z_##g##_3 = PK2(r_ + 6); }
    G16(LOADZ)

    // ---- wdiag_t = sum_i W1[i,t] * W2[t,i]  (exact fp32, one-time) ----
    float wd = 0.f;
    {
        const float* w2r_ = W2 + t * 128;
#define WD4(g) { wd = fmaf(w1_##g##_0, w2r_[4*(g)+0], wd); \
                 wd = fmaf(w1_##g##_1, w2r_[4*(g)+1], wd); \
                 wd = fmaf(w1_##g##_2, w2r_[4*(g)+2], wd); \
                 wd = fmaf(w1_##g##_3, w2r_[4*(g)+3], wd); }
        G32(WD4)
    }

    const float b1k = b1[t];
    const float u1k = u1[t];
    const float b2j = b2[j];

    const int ns = nsp[0];
    const float dt = 1.f / (float)ns;

    // ---- init state + log_px0 sum of squares ----
    if (t < 128) {
        float xv = x0[s * 128 + t];
        ys[t] = xv;
        xs[t] = xv;
        float sq = xv * xv;
#pragma unroll
        for (int off = 32; off; off >>= 1) sq += __shfl_xor(sq, off, 64);
        if (lane == 0) wred[8 + wid] = sq;
    }
    __syncthreads();
    const float sumsq = wred[8] + wred[9];
    float ld_acc = 0.f, kl_acc = 0.f;

    // ---- per-eval compute groups (all indices compile-time constant) ----
#define H4(g) { float4 xv_ = *(const float4*)&xs[4*(g)]; /* LDS broadcast */ \
    h0 = fmaf(xv_.x, w1_##g##_0, h0); h1 = fmaf(xv_.y, w1_##g##_1, h1); \
    h2 = fmaf(xv_.z, w1_##g##_2, h2); h3 = fmaf(xv_.w, w1_##g##_3, h3); }

#define LO16(u) __uint_as_float((u) << 16)
#define HI16(u) __uint_as_float((u) & 0xffff0000u)
#define P8(g) { float4 av_ = *(const float4*)&aL[kb + 8*(g)];     /* broadcast */ \
                float4 bv_ = *(const float4*)&aL[kb + 8*(g) + 4]; \
    p0 = fmaf(av_.x, LO16(z_##g##_0), p0); p1 = fmaf(av_.y, HI16(z_##g##_0), p1); \
    p2 = fmaf(av_.z, LO16(z_##g##_1), p2); p3 = fmaf(av_.w, HI16(z_##g##_1), p3); \
    p0 = fmaf(bv_.x, LO16(z_##g##_2), p0); p1 = fmaf(bv_.y, HI16(z_##g##_2), p1); \
    p2 = fmaf(bv_.z, LO16(z_##g##_3), p2); p3 = fmaf(bv_.w, HI16(z_##g##_3), p3); }

// One RHS eval: reads xs, writes kx[STAGE], klpS/kklS[STAGE]. 3 internal barriers.
#define EVAL(STAGE, TVAL)                                                      \
    {                                                                          \
        float h0 = 0.f, h1 = 0.f, h2 = 0.f, h3 = 0.f;                          \
        G32(H4)                                                                \
        float hh = fmaf((TVAL), u1k, b1k) + ((h0 + h1) + (h2 + h3));           \
        float ee = __expf(2.f * hh);                                           \
        float aa = 1.f - 2.f / (ee + 1.f);       /* tanh */                    \
        aL[t] = aa;                                                            \
        float trp = (1.f - aa * aa) * wd;                                      \
        _Pragma("unroll")                                                      \
        for (int off = 32; off; off >>= 1) trp += __shfl_xor(trp, off, 64);    \
        if (lane == 0) wred[wid] = trp;                                        \
        __syncthreads();                          /* B1: a + tr partials */    \
        float p0 = 0.f, p1 = 0.f, p2 = 0.f, p3 = 0.f;                          \
        G16(P8)                                                                \
        part[q][j] = (p0 + p1) + (p2 + p3);                                    \
        __syncthreads();                          /* B2: partials ready */     \
        if (t < 128) {                                                         \
            float dx = ((part[0][t] + part[1][t]) + (part[2][t] + part[3][t])) \
                       + b2j;                                                  \
            kx[STAGE][t] = dx;                                                 \
            float xd = xs[t] * dx;                                             \
            _Pragma("unroll")                                                  \
            for (int off = 32; off; off >>= 1) xd += __shfl_xor(xd, off, 64);  \
            if (lane == 0) wred[8 + wid] = xd;                                 \
        }                                                                      \
        __syncthreads();                          /* B3: kx + dot partials */  \
        if (t == 0) {                                                          \
            float tr = ((wred[0] + wred[1]) + (wred[2] + wred[3]))             \
                     + ((wred[4] + wred[5]) + (wred[6] + wred[7]));            \
            float dotv = wred[8] + wred[9];                                    \
            klpS[STAGE] = -tr;                                                 \
            kklS[STAGE] = dotv - tr;                                           \
        }                                                                      \
    }

    for (int n = 0; n < ns; ++n) {
        const float tn = (float)n;

        EVAL(0, dt * tn);
        if (t < 128) xs[t] = fmaf(dt, 0.2f * kx[0][t], ys[t]);
        __syncthreads();

        EVAL(1, dt * (tn + 0.2f));
        if (t < 128) xs[t] = fmaf(dt, 0.075f * kx[0][t] + 0.225f * kx[1][t], ys[t]);
        __syncthreads();

        EVAL(2, dt * (tn + 0.3f));
        if (t < 128) xs[t] = fmaf(dt,
              (float)(44.0/45.0)  * kx[0][t] + (float)(-56.0/15.0) * kx[1][t]
            + (float)(32.0/9.0)   * kx[2][t], ys[t]);
        __syncthreads();

        EVAL(3, dt * (tn + 0.8f));
        if (t < 128) xs[t] = fmaf(dt,
              (float)(19372.0/6561.0)  * kx[0][t] + (float)(-25360.0/2187.0) * kx[1][t]
            + (float)(64448.0/6561.0)  * kx[2][t] + (float)(-212.0/729.0)    * kx[3][t], ys[t]);
        __syncthreads();

        EVAL(4, dt * (tn + (float)(8.0/9.0)));
        if (t < 128) xs[t] = fmaf(dt,
              (float)(9017.0/3168.0)   * kx[0][t] + (float)(-355.0/33.0)     * kx[1][t]
            + (float)(46732.0/5247.0)  * kx[2][t] + (float)(49.0/176.0)      * kx[3][t]
            + (float)(-5103.0/18656.0) * kx[4][t], ys[t]);
        __syncthreads();

        EVAL(5, dt * (tn + 1.0f));
        if (t < 128) {
            float sum = (float)(35.0/384.0)    * kx[0][t] + (float)(500.0/1113.0)   * kx[2][t]
                      + (float)(125.0/192.0)   * kx[3][t] + (float)(-2187.0/6784.0) * kx[4][t]
                      + (float)(11.0/84.0)     * kx[5][t];
            float yv = fmaf(dt, sum, ys[t]);
            ys[t] = yv;
            xs[t] = yv;
        }
        if (t == 0) {
            ld_acc += dt * ((float)(35.0/384.0)  * klpS[0] + (float)(500.0/1113.0)   * klpS[2]
                          + (float)(125.0/192.0) * klpS[3] + (float)(-2187.0/6784.0) * klpS[4]
                          + (float)(11.0/84.0)   * klpS[5]);
            kl_acc += dt * ((float)(35.0/384.0)  * kklS[0] + (float)(500.0/1113.0)   * kklS[2]
                          + (float)(125.0/192.0) * kklS[3] + (float)(-2187.0/6784.0) * kklS[4]
                          + (float)(11.0/84.0)   * kklS[5]);
        }
        __syncthreads();
    }

    // ---- outputs: z (B,D) | log_px (B) | kl (B) ----
    if (t < 128) out[s * 128 + t] = ys[t];
    if (t == 0) {
        const float LOG2PI = 1.8378770664093454f;
        float lpx0 = -0.5f * sumsq - 0.5f * 128.f * LOG2PI;
        out[nB * 128 + s]      = lpx0 + ld_acc;
        out[nB * 128 + nB + s] = kl_acc;
    }
}

extern "C" void kernel_launch(void* const* d_in, const int* in_sizes, int n_in,
                              void* d_out, int out_size, void* d_ws, size_t ws_size,
                              hipStream_t stream) {
    const float* x0 = (const float*)d_in[0];
    const float* W1 = (const float*)d_in[1];
    const float* b1 = (const float*)d_in[2];
    const float* u1 = (const float*)d_in[3];
    const float* W2 = (const float*)d_in[4];
    const float* b2 = (const float*)d_in[5];
    const int*  nsp = (const int*)d_in[6];
    float* out = (float*)d_out;
    const int nB = in_sizes[0] / 128;   // 128 samples

    hipLaunchKernelGGL(vi_node_kernel, dim3(nB), dim3(TPB), 0, stream,
                       x0, W1, b1, u1, W2, b2, nsp, out, nB);
}

// Round 5
// 232.782 us; speedup vs baseline: 3.1479x; 3.0793x over previous
//
#include <hip/hip_runtime.h>

#define TPB 512

typedef _Float16 hf2 __attribute__((ext_vector_type(2)));

__device__ __forceinline__ hf2 as_h2(unsigned u) { return __builtin_bit_cast(hf2, u); }
__device__ __forceinline__ unsigned pk2h(float a, float b) {
    unsigned la = (unsigned)__builtin_bit_cast(unsigned short, (_Float16)a);
    unsigned hb = (unsigned)__builtin_bit_cast(unsigned short, (_Float16)b);
    return la | (hb << 16);
}
__device__ __forceinline__ unsigned short h16(float a) {
    return __builtin_bit_cast(unsigned short, (_Float16)a);
}
#define FDOT2(w, x, acc) __builtin_amdgcn_fdot2(as_h2(w), as_h2(x), (acc), false)

#define G16(M) M(0) M(1) M(2) M(3) M(4) M(5) M(6) M(7) M(8) M(9) M(10) M(11) \
  M(12) M(13) M(14) M(15)

#define RED64(v) { v += __shfl_xor(v,32,64); v += __shfl_xor(v,16,64); \
  v += __shfl_xor(v,8,64); v += __shfl_xor(v,4,64); v += __shfl_xor(v,2,64); \
  v += __shfl_xor(v,1,64); }

// One block per sample (128 blocks). Register budget kept UNDER the 128-VGPR
// wall the backend enforces (3 rounds of >128 designs all spilled):
//   - W2 col j f16-packed in 64 named scalar u32 regs (only persistent state)
//   - W1 in LDS as f16, W1L[c][t] = W1[8c..8c+7][t] (16B) -> 16 ds_read_b128
//     per eval, bank-conflict-free (lane l -> bank 4l mod 32, 8-lane groups
//     cover all 32 banks -> 8-clk floor per wave read)
//   - both matvecs via v_dot2_f32_f16 (fp32 accumulate)
// 3 barriers/eval; serial log-det tail once per STEP via stage-indexed,
// step-parity double-buffered partial slots.
__global__ __launch_bounds__(TPB, 1) void vi_node_kernel(
    const float* __restrict__ x0, const float* __restrict__ W1,
    const float* __restrict__ b1, const float* __restrict__ u1,
    const float* __restrict__ W2, const float* __restrict__ b2,
    const int* __restrict__ nsp, float* __restrict__ out, int nB)
{
    const int s    = blockIdx.x;
    const int t    = threadIdx.x;
    const int j    = t & 127;
    const int q    = t >> 7;
    const int kb   = q << 7;
    const int lane = t & 63;
    const int wid  = t >> 6;

    __shared__ uint4 W1L[16 * 512];                 // 128 KB, f16 W1 columns
    __shared__ __align__(16) float    xs32[128];    // stage input, fp32
    __shared__ __align__(16) unsigned xshU[64];     // stage input, f16-packed
    __shared__ __align__(16) float    ys[128];      // base state y_n
    __shared__ __align__(16) unsigned aLhU[256];    // tanh acts, f16-packed
    __shared__ __align__(16) float    part[4][128]; // dxdt partials
    __shared__ __align__(16) float    kx[6][128];   // RK stage slopes
    __shared__ float wredT[2][6][8];                // trace partials [par][stage][wave]
    __shared__ float wredX[2][6][2];                // x.dx partials  [par][stage][wave0/1]
    __shared__ float sqred[2];

    // ---- build W1L (global reads coalesced across t for each row) ----
#pragma unroll
    for (int c = 0; c < 16; ++c) {
        const float* gp = W1 + (8 * c) * 512 + t;
        uint4 wv;
        wv.x = pk2h(gp[0],        gp[512]);
        wv.y = pk2h(gp[2 * 512],  gp[3 * 512]);
        wv.z = pk2h(gp[4 * 512],  gp[5 * 512]);
        wv.w = pk2h(gp[6 * 512],  gp[7 * 512]);
        W1L[c * 512 + t] = wv;
    }

    // ---- W2 column j, rows kb..kb+127, f16 pairs in named scalar regs ----
#define DECLZ(g) unsigned z_##g##_0, z_##g##_1, z_##g##_2, z_##g##_3;
    G16(DECLZ)
#define PKW2(r) pk2h(W2[(r) * 128 + j], W2[((r) + 1) * 128 + j])
#define LOADZ(g) { const int r_ = kb + 8 * (g); \
    z_##g##_0 = PKW2(r_);     z_##g##_1 = PKW2(r_ + 2); \
    z_##g##_2 = PKW2(r_ + 4); z_##g##_3 = PKW2(r_ + 6); }
    G16(LOADZ)

    const float b1k = b1[t];
    const float u1k = u1[t];
    const float b2j = b2[j];

    const int ns = nsp[0];
    const float dt = 1.f / (float)ns;

    // ---- x0 init + log_px0 sum of squares ----
    if (t < 128) {
        float xv = x0[s * 128 + t];
        ys[t] = xv;
        xs32[t] = xv;
        ((unsigned short*)xshU)[t] = h16(xv);
        float sq = xv * xv;
        RED64(sq)
        if (lane == 0) sqred[wid] = sq;
    }
    __syncthreads();   // W1L + xsh + sqred ready

    // ---- wdiag_t = sum_i W1[i,t]*W2[t,i] via f16 dot2 (one-time) ----
    float wd = 0.f;
    {
        const float4* w2r4 = (const float4*)(W2 + t * 128);
#pragma unroll
        for (int c = 0; c < 16; ++c) {
            uint4 wv = W1L[c * 512 + t];
            float4 a4 = w2r4[2 * c], b4 = w2r4[2 * c + 1];
            wd = FDOT2(wv.x, pk2h(a4.x, a4.y), wd);
            wd = FDOT2(wv.y, pk2h(a4.z, a4.w), wd);
            wd = FDOT2(wv.z, pk2h(b4.x, b4.y), wd);
            wd = FDOT2(wv.w, pk2h(b4.z, b4.w), wd);
        }
    }
    const float sumsq = sqred[0] + sqred[1];
    float ld_acc = 0.f, kl_acc = 0.f;   // thread-0 accumulators

    // ---- per-eval compute groups ----
#define H8(c) { uint4 w_ = W1L[(c) * 512 + t]; \
    const uint4 xv_ = *(const uint4*)&xshU[(c) * 4]; \
    m0 = FDOT2(w_.x, xv_.x, m0); m1 = FDOT2(w_.y, xv_.y, m1); \
    m2 = FDOT2(w_.z, xv_.z, m2); m3 = FDOT2(w_.w, xv_.w, m3); }

#define P8(g) { const uint4 av_ = *(const uint4*)&aLhU[q * 64 + (g) * 4]; \
    p0 = FDOT2(z_##g##_0, av_.x, p0); p1 = FDOT2(z_##g##_1, av_.y, p1); \
    p2 = FDOT2(z_##g##_2, av_.z, p2); p3 = FDOT2(z_##g##_3, av_.w, p3); }

#define K(sidx) kx[sidx][t]

// One RHS eval + in-place state advance. 3 barriers.
#define EVAL(STAGE, TVAL, XNEW, EXTRA)                                         \
    {                                                                          \
        float m0 = 0.f, m1 = 0.f, m2 = 0.f, m3 = 0.f;                          \
        H8(0) H8(1) H8(2) H8(3) H8(4) H8(5) H8(6) H8(7)                        \
        H8(8) H8(9) H8(10) H8(11) H8(12) H8(13) H8(14) H8(15)                  \
        float hh = fmaf((TVAL), u1k, b1k) + ((m0 + m1) + (m2 + m3));           \
        float ee = __expf(2.f * hh);                                           \
        float aa = 1.f - 2.f / (ee + 1.f);       /* tanh */                    \
        ((unsigned short*)aLhU)[t] = h16(aa);                                  \
        float trp = (1.f - aa * aa) * wd;                                      \
        RED64(trp)                                                             \
        if (lane == 0) wredT[par][STAGE][wid] = trp;                           \
        __syncthreads();                          /* B1: aL + trace ready */   \
        float p0 = 0.f, p1 = 0.f, p2 = 0.f, p3 = 0.f;                          \
        P8(0) P8(1) P8(2) P8(3) P8(4) P8(5) P8(6) P8(7)                        \
        P8(8) P8(9) P8(10) P8(11) P8(12) P8(13) P8(14) P8(15)                  \
        part[q][j] = (p0 + p1) + (p2 + p3);                                    \
        __syncthreads();                          /* B2: partials ready */     \
        if (t < 128) {                                                         \
            float dx = ((part[0][t] + part[1][t]) + (part[2][t] + part[3][t])) \
                       + b2j;                                                  \
            kx[STAGE][t] = dx;                                                 \
            float xd = xs32[t] * dx;                                           \
            RED64(xd)                                                          \
            if (lane == 0) wredX[par][STAGE][wid] = xd;                        \
            float xnew = (XNEW);                                               \
            xs32[t] = xnew;                                                    \
            ((unsigned short*)xshU)[t] = h16(xnew);                            \
            EXTRA                                                              \
        }                                                                      \
        __syncthreads();                          /* B3: state advanced */     \
    }

    for (int n = 0; n < ns; ++n) {
        const float tn = (float)n;
        const int par = n & 1;

        EVAL(0, dt * tn,
             fmaf(dt, 0.2f * dx, ys[t]), ;)

        EVAL(1, dt * (tn + 0.2f),
             ys[t] + dt * (0.075f * K(0) + 0.225f * dx), ;)

        EVAL(2, dt * (tn + 0.3f),
             ys[t] + dt * ((float)(44.0/45.0)  * K(0) + (float)(-56.0/15.0) * K(1)
                         + (float)(32.0/9.0)   * dx), ;)

        EVAL(3, dt * (tn + 0.8f),
             ys[t] + dt * ((float)(19372.0/6561.0) * K(0) + (float)(-25360.0/2187.0) * K(1)
                         + (float)(64448.0/6561.0) * K(2) + (float)(-212.0/729.0)    * dx), ;)

        EVAL(4, dt * (tn + (float)(8.0/9.0)),
             ys[t] + dt * ((float)(9017.0/3168.0)  * K(0) + (float)(-355.0/33.0)     * K(1)
                         + (float)(46732.0/5247.0) * K(2) + (float)(49.0/176.0)      * K(3)
                         + (float)(-5103.0/18656.0)* dx), ;)

        EVAL(5, dt * (tn + 1.0f),
             ys[t] + dt * ((float)(35.0/384.0)     * K(0) + (float)(500.0/1113.0)   * K(2)
                         + (float)(125.0/192.0)    * K(3) + (float)(-2187.0/6784.0) * K(4)
                         + (float)(11.0/84.0)      * dx),
             ys[t] = xnew;)

        // serial tail once per STEP: weighted log-det / KL accumulation.
        // wredT/wredX[par] slots stable: next same-parity write is 2 steps away.
        if (t == 0) {
#define TAILS(sidx, bw) { \
            float tr_ = ((wredT[par][sidx][0] + wredT[par][sidx][1])  \
                       + (wredT[par][sidx][2] + wredT[par][sidx][3])) \
                      + ((wredT[par][sidx][4] + wredT[par][sidx][5])  \
                       + (wredT[par][sidx][6] + wredT[par][sidx][7])); \
            float dv_ = wredX[par][sidx][0] + wredX[par][sidx][1]; \
            ld_acc += dt * (bw) * (-tr_); \
            kl_acc += dt * (bw) * (dv_ - tr_); }
            TAILS(0, (float)(35.0/384.0))
            TAILS(2, (float)(500.0/1113.0))
            TAILS(3, (float)(125.0/192.0))
            TAILS(4, (float)(-2187.0/6784.0))
            TAILS(5, (float)(11.0/84.0))
        }
    }

    // ---- outputs: z (B,D) | log_px (B) | kl (B) ----
    if (t < 128) out[s * 128 + t] = ys[t];
    if (t == 0) {
        const float LOG2PI = 1.8378770664093454f;
        float lpx0 = -0.5f * sumsq - 0.5f * 128.f * LOG2PI;
        out[nB * 128 + s]      = lpx0 + ld_acc;
        out[nB * 128 + nB + s] = kl_acc;
    }
}

extern "C" void kernel_launch(void* const* d_in, const int* in_sizes, int n_in,
                              void* d_out, int out_size, void* d_ws, size_t ws_size,
                              hipStream_t stream) {
    const float* x0 = (const float*)d_in[0];
    const float* W1 = (const float*)d_in[1];
    const float* b1 = (const float*)d_in[2];
    const float* u1 = (const float*)d_in[3];
    const float* W2 = (const float*)d_in[4];
    const float* b2 = (const float*)d_in[5];
    const int*  nsp = (const int*)d_in[6];
    float* out = (float*)d_out;
    const int nB = in_sizes[0] / 128;   // 128 samples

    hipLaunchKernelGGL(vi_node_kernel, dim3(nB), dim3(TPB), 0, stream,
                       x0, W1, b1, u1, W2, b2, nsp, out, nB);
}